// Round 8
// baseline (263.162 us; speedup 1.0000x reference)
//
#include <hip/hip_runtime.h>

typedef float floatx4 __attribute__((ext_vector_type(4)));
typedef float floatx2 __attribute__((ext_vector_type(2)));

#define BB 32
#define HH 56
#define WW 56
#define CC 256
#define PSTRIP 4
#define WSTRIPS 14                      // 56/4
#define HTILE 2                         // rows per block (2 rows x 2 halves)
#define HTILES 28                       // 56/2
#define BLOCKS_PER_IMG (HTILES * WSTRIPS)  // 392

// R14 = R13 resubmitted (R13 hit an infra "container failed twice", same
// transient pattern as R9; kernel reviewed again, no correctness hazard:
// clamped tap addresses always in-bounds, (t*m)^2 = t^2*m reproduces
// SAME-zero-padding exactly, hm<HH / hp>=0 structural).
//
// R13 theory: lane = channel PAIR (2ch), wave = half-pixel (128ch).
// R10/R11/R12 showed the 4ch/lane working set (10x16B in-flight loads =
// 40 dest regs + squares + addressing) structurally needs ~70+ VGPR; the
// allocator relaxes occupancy instead of spilling. Empirical law R6-R12:
// VGPR>=72 -> 2.3 waves/SIMD -> 1.6 TB/s -> ~94us; VGPR<=48 -> >=4.4
// waves/SIMD -> >=3.4 TB/s even WITH spill traffic.
// Structural fix: halve lane width. Tap destinations 8x2=16 regs (ALL 8
// in flight, no batching), acc/cxo 2 each; center group 2xb128 (8, 4-way
// L1 broadcast); est. live ~56 < 64 = budget from the 20KB LDS pin
// (160/20 = exactly 8 blocks/CU -> allocator target 8 waves/SIMD).
// Taps BRANCH-FREE: clamped addresses + multiplicative 0/1 masks; all 10
// loads issue back-to-back, one wait point per pixel instead of 3.
// Kept: weights+consts in LDS (0 bank conflicts), XCD pinning, NT stores.
// Block = 4 waves: wid>>1 = row (2 rows), wid&1 = channel half.
// Tripwires: VGPR_Count <= 64; FETCH ~50MB / WRITE ~100MB (inflation =
// spill); occupancy 29 -> 50-80%; dur 94 -> 45-60us.
__global__ __launch_bounds__(256) void dn_kernel(
    const float* __restrict__ x,
    const float* __restrict__ gk_g,
    const float* __restrict__ gs_g,
    const float* __restrict__ beta,
    const float* __restrict__ beta_o,
    const float* __restrict__ gamma_o,
    const int* __restrict__ sdist,
    float* __restrict__ out)
{
    // 20KB: rows 0-7 gk, 8-15 gsw, 16 beta+BETA_MIN, 17 gamma_o, 18 beta_o,
    // row 19 = occupancy-pinning pad (160/20 = exactly 8 blocks/CU).
    __shared__ float lw[20 * CC];

    const int tid = threadIdx.x;

    // Cooperative stage: 19 rows x 256 floats, dwordx4 per thread-iter.
    for (int idx = tid; idx < 19 * 64; idx += 256) {
        const int r  = idx >> 6;
        const int cq = (idx & 63) << 2;
        floatx4 v;
        if (r < 8) {
            v = *reinterpret_cast<const floatx4*>(gk_g + r * CC + cq);
        } else if (r < 16) {
            const int t   = r - 8;
            const int pos = t + (t >= 4 ? 1 : 0);   // skip center of 3x3
            v = *reinterpret_cast<const floatx4*>(gs_g + pos * CC + cq);
        } else if (r == 16) {
            v = *reinterpret_cast<const floatx4*>(beta + cq);
            v += 1e-6f;                             // fold BETA_MIN here
        } else if (r == 17) {
            v = *reinterpret_cast<const floatx4*>(gamma_o + cq);
        } else {
            v = *reinterpret_cast<const floatx4*>(beta_o + cq);
        }
        *reinterpret_cast<floatx4*>(&lw[r * CC + cq]) = v;
    }

    const int d    = sdist[0];                 // surround_dist (=1)
    const int xcd  = blockIdx.x & 7;
    const int q    = blockIdx.x >> 3;          // 0..1567
    const int b    = xcd + ((q / BLOCKS_PER_IMG) << 3);
    const int t0   = q % BLOCKS_PER_IMG;
    const int wid  = tid >> 6;                 // wave id 0..3
    const int h    = (t0 / WSTRIPS) * HTILE + (wid >> 1);
    const int w0   = (t0 % WSTRIPS) * PSTRIP;
    const int half = wid & 1;                  // channel half 0/1
    const int lane = tid & 63;
    const int c0   = (half << 7) + (lane << 1);   // own channel pair
    const int cg   = c0 & ~7;                  // group base (8 ch)

    const float* xb = x + (size_t)b * HH * WW * CC;

    // Hoisted clamped row geometry + validity (wave-uniform).
    const int hm  = h - d, hp = h + d;
    const float vrm = (hm >= 0) ? 1.f : 0.f;   // hm < HH always (h<56, d>=1)
    const float vrp = (hp < HH) ? 1.f : 0.f;
    const int hmc = (hm >= 0) ? hm : 0;
    const int hpc = (hp < HH) ? hp : (HH - 1);
    const float* rowm = xb + (size_t)hmc * (WW * CC);
    const float* row0 = xb + (size_t)h   * (WW * CC);
    const float* rowp = xb + (size_t)hpc * (WW * CC);
    float*       orow = out + ((size_t)(b * HH + h) * WW) * CC;
    const float* wk   = lw + c0;               // per-lane LDS base

    __syncthreads();

#pragma unroll
    for (int j = 0; j < PSTRIP; ++j) {
        const int w  = w0 + j;
        const int wm = w - d, wp = w + d;
        const float vwm = (wm >= 0) ? 1.f : 0.f;
        const float vwp = (wp < WW) ? 1.f : 0.f;
        const int wmc = (wm >= 0) ? wm : 0;
        const int wpc = (wp < WW) ? wp : (WW - 1);
        const int colm = wmc * CC + c0;        // clamped left column
        const int col0 = w   * CC + c0;        // own column
        const int colp = wpc * CC + c0;        // clamped right column

        // ---- all 10 loads issued back-to-back, branch-free ----
        floatx2 t0v = *reinterpret_cast<const floatx2*>(rowm + colm);
        floatx2 t1v = *reinterpret_cast<const floatx2*>(rowm + col0);
        floatx2 t2v = *reinterpret_cast<const floatx2*>(rowm + colp);
        floatx2 t3v = *reinterpret_cast<const floatx2*>(row0 + colm);
        floatx2 t4v = *reinterpret_cast<const floatx2*>(row0 + colp);
        floatx2 t5v = *reinterpret_cast<const floatx2*>(rowp + colm);
        floatx2 t6v = *reinterpret_cast<const floatx2*>(rowp + col0);
        floatx2 t7v = *reinterpret_cast<const floatx2*>(rowp + colp);
        const float* cbase = row0 + w * CC + cg;
        floatx4 cxa = *reinterpret_cast<const floatx4*>(cbase);
        floatx4 cxb = *reinterpret_cast<const floatx4*>(cbase + 4);

        // validity masks (0/1 floats); (tp*m)^2 == tp^2*m
        const float m0 = vrm * vwm, m2 = vrm * vwp;
        const float m5 = vrp * vwm, m7 = vrp * vwp;

        // center: select own raw pair; squares of the full 8-ch group
        const floatx4 s4 = (lane & 2) ? cxb : cxa;
        floatx2 cxo;
        cxo[0] = (lane & 1) ? s4[2] : s4[0];
        cxo[1] = (lane & 1) ? s4[3] : s4[1];
        const floatx4 sqa = cxa * cxa, sqb = cxb * cxb;

        // Pk: 8 group inputs x own 2 outputs, weights streamed from LDS
        floatx2 acc = *reinterpret_cast<const floatx2*>(wk + 16 * CC); // beta
#pragma unroll
        for (int i = 0; i < 4; ++i)
            acc += sqa[i] * *reinterpret_cast<const floatx2*>(wk + i * CC);
#pragma unroll
        for (int i = 0; i < 4; ++i)
            acc += sqb[i] * *reinterpret_cast<const floatx2*>(wk + (4 + i) * CC);

        // Ps: 8 masked taps on own pair
        t0v *= m0;  t1v *= vrm; t2v *= m2;  t3v *= vwm;
        t4v *= vwp; t5v *= m5;  t6v *= vrp; t7v *= m7;
        acc += (t0v * t0v) * *reinterpret_cast<const floatx2*>(wk +  8 * CC);
        acc += (t1v * t1v) * *reinterpret_cast<const floatx2*>(wk +  9 * CC);
        acc += (t2v * t2v) * *reinterpret_cast<const floatx2*>(wk + 10 * CC);
        acc += (t3v * t3v) * *reinterpret_cast<const floatx2*>(wk + 11 * CC);
        acc += (t4v * t4v) * *reinterpret_cast<const floatx2*>(wk + 12 * CC);
        acc += (t5v * t5v) * *reinterpret_cast<const floatx2*>(wk + 13 * CC);
        acc += (t6v * t6v) * *reinterpret_cast<const floatx2*>(wk + 14 * CC);
        acc += (t7v * t7v) * *reinterpret_cast<const floatx2*>(wk + 15 * CC);

        // epilogue: gov/bov from LDS (transient regs)
        const floatx2 gov = *reinterpret_cast<const floatx2*>(wk + 17 * CC);
        const floatx2 bov = *reinterpret_cast<const floatx2*>(wk + 18 * CC);
        floatx2 res;
        res[0] = cxo[0] * __builtin_amdgcn_rsqf(acc[0]) * gov[0] + bov[0];
        res[1] = cxo[1] * __builtin_amdgcn_rsqf(acc[1]) * gov[1] + bov[1];

        floatx2* dst = reinterpret_cast<floatx2*>(orow + w * CC + c0);
        __builtin_nontemporal_store(res, dst);
    }
}

extern "C" void kernel_launch(void* const* d_in, const int* in_sizes, int n_in,
                              void* d_out, int out_size, void* d_ws, size_t ws_size,
                              hipStream_t stream) {
    const float* x       = (const float*)d_in[0];
    const float* gamma_k = (const float*)d_in[1];
    const float* gamma_s = (const float*)d_in[2];
    const float* beta    = (const float*)d_in[3];
    const float* beta_o  = (const float*)d_in[4];
    const float* gamma_o = (const float*)d_in[5];
    const int*   sdist   = (const int*)d_in[6];
    float* out = (float*)d_out;

    const int blocks = BB * BLOCKS_PER_IMG;   // 12544
    dn_kernel<<<blocks, 256, 0, stream>>>(x, gamma_k, gamma_s, beta,
                                          beta_o, gamma_o, sdist, out);
}